// Round 7
// baseline (20194.835 us; speedup 1.0000x reference)
//
#include <hip/hip_runtime.h>
#include <cstdint>
#include <cstddef>

#define T_SEQ 2048
#define BATCH 16
#define DIM   512
#define HID   512
#define NCOL  2048            // 4H per direction
#define XROW  520             // 512 + 8 pad (bf16) -> only 2-way LDS aliasing

typedef __attribute__((ext_vector_type(8))) short          s8v;
typedef __attribute__((ext_vector_type(4))) float          f4v;
typedef __attribute__((ext_vector_type(4))) unsigned short h4v;

#define HXBASE(d, s) (((size_t)((d) * 2 + (s)) * BATCH) * HID)

__device__ __forceinline__ unsigned short f2b(float f) {
  unsigned u = __builtin_bit_cast(unsigned, f);
  return (unsigned short)((u + 0x7fffu + ((u >> 16) & 1u)) >> 16);  // RNE
}

#define MFMA16(a, w, c) __builtin_amdgcn_mfma_f32_16x16x32_bf16((a), (w), (c), 0, 0, 0)

// K=512 over AX (wi) + optional K=512 over AH (wh), 4 chains -> OUT (f4v)
#define GEMM_DIR(AX, AH, WI, WH, WITHH, OUT)                                   \
  {                                                                            \
    f4v d0 = {0,0,0,0}, d1 = {0,0,0,0}, d2 = {0,0,0,0}, d3 = {0,0,0,0};        \
    {                                                                          \
      const unsigned short* ap = &AX[arow][koff];                              \
      _Pragma("unroll")                                                        \
      for (int kc = 0; kc < 16; kc += 4) {                                     \
        d0 = MFMA16(*(const s8v*)(ap + (kc + 0) * 32), WI[kc + 0], d0);        \
        d1 = MFMA16(*(const s8v*)(ap + (kc + 1) * 32), WI[kc + 1], d1);        \
        d2 = MFMA16(*(const s8v*)(ap + (kc + 2) * 32), WI[kc + 2], d2);        \
        d3 = MFMA16(*(const s8v*)(ap + (kc + 3) * 32), WI[kc + 3], d3);        \
      }                                                                        \
    }                                                                          \
    if (WITHH) {                                                               \
      const unsigned short* ap = &AH[arow][koff];                              \
      _Pragma("unroll")                                                        \
      for (int kc = 0; kc < 16; kc += 4) {                                     \
        d0 = MFMA16(*(const s8v*)(ap + (kc + 0) * 32), WH[kc + 0], d0);        \
        d1 = MFMA16(*(const s8v*)(ap + (kc + 1) * 32), WH[kc + 1], d1);        \
        d2 = MFMA16(*(const s8v*)(ap + (kc + 2) * 32), WH[kc + 2], d2);        \
        d3 = MFMA16(*(const s8v*)(ap + (kc + 3) * 32), WH[kc + 3], d3);        \
      }                                                                        \
    }                                                                          \
    OUT = (d0 + d1) + (d2 + d3);                                               \
  }

#define LOAD_W(DST, SRC)                                                       \
  _Pragma("unroll")                                                            \
  for (int kc = 0; kc < 16; ++kc) {                                            \
    const float* src = (SRC) + (size_t)(kc * 32 + kb) * NCOL + colW;           \
    s8v f;                                                                     \
    _Pragma("unroll")                                                          \
    for (int j = 0; j < 8; ++j) f[j] = (short)f2b(src[(size_t)j * NCOL]);      \
    DST[kc] = f;                                                               \
  }

// grid = 32 wgs x 256 thr. wg g owns j-block [g*16, g*16+16) for BOTH dirs.
// Both recurrences interleave in one wg so each direction's LLC exchange
// latency hides under the other direction's MFMA+gates+staging.
// Wave wv's 16 B-cols packed {gate, j0+4wv+q}; 2-round shfl_xor 4x4
// transpose delivers all 4 gates of one (b,j) to one thread.
// h exchange: epoch-tagged bf16 u32 in d_ws, ping-pong slots, relaxed
// agent-scope ld/st, tight poll (loads+check only).
__global__ __launch_bounds__(256, 1)
void lstm_dual(const float* __restrict__ x, const int* __restrict__ lengths,
               const float* __restrict__ Wi_f, const float* __restrict__ Wh_f,
               const float* __restrict__ b_f,
               const float* __restrict__ Wi_b, const float* __restrict__ Wh_b,
               const float* __restrict__ b_b,
               unsigned int* __restrict__ hx,
               float* __restrict__ out) {
  __shared__ unsigned short Ax0[BATCH][XROW], Ah0[BATCH][XROW];
  __shared__ unsigned short Ax1[BATCH][XROW], Ah1[BATCH][XROW];

  const int g    = (int)blockIdx.x;
  const int j0   = g * 16;
  const int tid  = (int)threadIdx.x;
  const int lane = tid & 63;
  const int wv   = tid >> 6;

  // staging/poll mapping: one (b, sub) per thread
  const int b   = tid >> 4;
  const int sub = tid & 15;
  const int len = lengths[b];

  // gate-math mapping (post-transpose): one (bm, jm) per thread
  const int bm   = 4 * (lane >> 4) + ((lane >> 2) & 3);
  const int jm   = j0 + 4 * wv + (lane & 3);
  const int lenm = lengths[bm];

  const float bi0 = b_f[0 * HID + jm], bf0 = b_f[1 * HID + jm];
  const float bg0 = b_f[2 * HID + jm], bo0 = b_f[3 * HID + jm];
  const float bi1 = b_b[0 * HID + jm], bf1 = b_b[1 * HID + jm];
  const float bg1 = b_b[2 * HID + jm], bo1 = b_b[3 * HID + jm];

  // ---- persistent W fragments, both dirs (256 VGPRs) ----
  s8v w0i[16], w0h[16], w1i[16], w1h[16];
  {
    const int colW = ((lane >> 2) & 3) * HID + j0 + 4 * wv + (lane & 3);
    const int kb   = (lane >> 4) * 8;
    LOAD_W(w0i, Wi_f)
    LOAD_W(w0h, Wh_f)
    LOAD_W(w1i, Wi_b)
    LOAD_W(w1h, Wh_b)
  }

  const int arow = lane & 15;
  const int koff = (lane >> 4) * 8;

  // transpose + gate math; returns h, updates c
  auto finish = [&](f4v acc, float& cst, float bi, float bfv, float bg, float bo) -> float {
    const int gb0 = (lane >> 2) & 1;
    float t0 = __shfl_xor(gb0 ? acc[0] : acc[1], 4);
    float t1 = __shfl_xor(gb0 ? acc[2] : acc[3], 4);
    if (gb0) { acc[0] = t0; acc[2] = t1; } else { acc[1] = t0; acc[3] = t1; }
    const int gb1 = (lane >> 3) & 1;
    float u0 = __shfl_xor(gb1 ? acc[0] : acc[2], 8);
    float u1 = __shfl_xor(gb1 ? acc[1] : acc[3], 8);
    if (gb1) { acc[0] = u0; acc[1] = u1; } else { acc[2] = u0; acc[3] = u1; }
    const float gi = acc[0] + bi;
    const float gf = acc[1] + bfv;
    const float gg = acc[2] + bg;
    const float go = acc[3] + bo;
    const float si = 1.f / (1.f + __expf(-gi));
    const float sf = 1.f / (1.f + __expf(-gf));
    const float so = 1.f / (1.f + __expf(-go));
    const float tg = 1.f - 2.f / (1.f + __expf(2.f * gg));
    cst = sf * cst + si * tg;
    const float tc = 1.f - 2.f / (1.f + __expf(2.f * cst));
    return so * tc;
  };

  // tight poll (loads + tag check only), then stage into AH
  auto poll_stage = [&](int d, unsigned e, unsigned short (&AH)[BATCH][XROW]) {
    const unsigned* hrow = hx + HXBASE(d, e & 1) + (size_t)b * HID;
    const unsigned long long msk = 0x0000FFFF0000FFFFULL;
    const unsigned long long pat = ((unsigned long long)e << 32) | e;
    unsigned long long hu[16];
    while (true) {
      bool ok = true;
#pragma unroll
      for (int r = 0; r < 8; ++r) {
        const int k = sub * 4 + r * 64;
        hu[2*r]   = __hip_atomic_load((const unsigned long long*)(hrow + k),
                                      __ATOMIC_RELAXED, __HIP_MEMORY_SCOPE_AGENT);
        hu[2*r+1] = __hip_atomic_load((const unsigned long long*)(hrow + k) + 1,
                                      __ATOMIC_RELAXED, __HIP_MEMORY_SCOPE_AGENT);
        ok &= ((hu[2*r] & msk) == pat) & ((hu[2*r+1] & msk) == pat);
      }
      if (ok) break;
      __builtin_amdgcn_s_sleep(1);
    }
#pragma unroll
    for (int r = 0; r < 8; ++r) {
      const int k = sub * 4 + r * 64;
      h4v p;
      p[0] = (unsigned short)(hu[2*r]   >> 16);
      p[1] = (unsigned short)(hu[2*r]   >> 48);
      p[2] = (unsigned short)(hu[2*r+1] >> 16);
      p[3] = (unsigned short)(hu[2*r+1] >> 48);
      *(h4v*)&AH[b][k] = p;
    }
  };

  // ---- prologue: stage x rows for t=0, both dirs ----
  {
    const float* xr0 = x + ((size_t)b * T_SEQ + 0) * DIM;
    const float* xr1 = x + ((size_t)b * T_SEQ + ((T_SEQ - 1 + len) & (T_SEQ - 1))) * DIM;
#pragma unroll
    for (int r = 0; r < 8; ++r) {
      const int k = sub * 4 + r * 64;
      f4v v0 = *(const f4v*)(xr0 + k);
      f4v v1 = *(const f4v*)(xr1 + k);
      h4v p0; p0[0] = f2b(v0[0]); p0[1] = f2b(v0[1]); p0[2] = f2b(v0[2]); p0[3] = f2b(v0[3]);
      h4v p1; p1[0] = f2b(v1[0]); p1[1] = f2b(v1[1]); p1[2] = f2b(v1[2]); p1[3] = f2b(v1[3]);
      *(h4v*)&Ax0[b][k] = p0;
      *(h4v*)&Ax1[b][k] = p1;
    }
  }
  __syncthreads();

  float c0 = 0.f, c1 = 0.f;

  for (int t = 0; t < T_SEQ; ++t) {
    const unsigned e = (unsigned)(t + 1);
    const bool notlast = (t + 1 < T_SEQ);

    // ---- dir0: MFMA -> gates -> publish h0 ASAP ----
    {
      f4v acc;
      GEMM_DIR(Ax0, Ah0, w0i, w0h, (t > 0), acc)
      const float h = finish(acc, c0, bi0, bf0, bg0, bo0);
      if (notlast) {
        const unsigned tagged = ((unsigned)f2b(h) << 16) | e;
        __hip_atomic_store(&hx[HXBASE(0, e & 1) + (size_t)bm * HID + jm], tagged,
                           __ATOMIC_RELAXED, __HIP_MEMORY_SCOPE_AGENT);
      }
      out[((size_t)bm * T_SEQ + t) * (2 * HID) + jm] = h;
    }

    // ---- issue x(t+1) loads for both dirs (hide under dir1 compute) ----
    f4v xv0[8], xv1[8];
    if (notlast) {
      const float* xr0 = x + ((size_t)b * T_SEQ + (t + 1)) * DIM;
      const float* xr1 = x + ((size_t)b * T_SEQ + ((T_SEQ - 2 - t + len) & (T_SEQ - 1))) * DIM;
#pragma unroll
      for (int r = 0; r < 8; ++r) {
        xv0[r] = *(const f4v*)(xr0 + sub * 4 + r * 64);
        xv1[r] = *(const f4v*)(xr1 + sub * 4 + r * 64);
      }
    }

    // ---- dir1: MFMA -> gates -> publish h1 ----
    {
      f4v acc;
      GEMM_DIR(Ax1, Ah1, w1i, w1h, (t > 0), acc)
      const float h = finish(acc, c1, bi1, bf1, bg1, bo1);
      if (notlast) {
        const unsigned tagged = ((unsigned)f2b(h) << 16) | e;
        __hip_atomic_store(&hx[HXBASE(1, e & 1) + (size_t)bm * HID + jm], tagged,
                           __ATOMIC_RELAXED, __HIP_MEMORY_SCOPE_AGENT);
      }
      const int tauo = (T_SEQ - 1 - t + lenm) & (T_SEQ - 1);
      out[((size_t)bm * T_SEQ + tauo) * (2 * HID) + HID + jm] = h;
    }

    if (!notlast) break;

    __syncthreads();   // SYNC-A: all waves done reading Ax*/Ah*

    // ---- stage x(t+1) into Ax0/Ax1 ----
#pragma unroll
    for (int r = 0; r < 8; ++r) {
      const int k = sub * 4 + r * 64;
      h4v p0; p0[0] = f2b(xv0[r][0]); p0[1] = f2b(xv0[r][1]);
              p0[2] = f2b(xv0[r][2]); p0[3] = f2b(xv0[r][3]);
      h4v p1; p1[0] = f2b(xv1[r][0]); p1[1] = f2b(xv1[r][1]);
              p1[2] = f2b(xv1[r][2]); p1[3] = f2b(xv1[r][3]);
      *(h4v*)&Ax0[b][k] = p0;
      *(h4v*)&Ax1[b][k] = p1;
    }

    // ---- polls: h0 flew during dir1 compute; h1 during h0's staging ----
    poll_stage(0, e, Ah0);
    poll_stage(1, e, Ah1);

    __syncthreads();   // SYNC-B: next step's operands staged
  }
}

extern "C" void kernel_launch(void* const* d_in, const int* in_sizes, int n_in,
                              void* d_out, int out_size, void* d_ws, size_t ws_size,
                              hipStream_t stream) {
  const float* x    = (const float*)d_in[0];
  const int*   len  = (const int*)d_in[1];
  const float* Wi_f = (const float*)d_in[2];
  const float* Wh_f = (const float*)d_in[3];
  const float* b_f  = (const float*)d_in[4];
  const float* Wi_b = (const float*)d_in[5];
  const float* Wh_b = (const float*)d_in[6];
  const float* b_b  = (const float*)d_in[7];
  float* out = (float*)d_out;
  unsigned int* hx = (unsigned int*)d_ws;   // [2][2][16][512] u32 = 128 KB

  hipMemsetAsync(d_ws, 0, (size_t)2 * 2 * BATCH * HID * 4, stream);
  hipLaunchKernelGGL(lstm_dual, dim3(32), dim3(256), 0, stream,
                     x, len, Wi_f, Wh_f, b_f, Wi_b, Wh_b, b_b, hx, out);
}

// Round 9
// 6398.692 us; speedup vs baseline: 3.1561x; 3.1561x over previous
//
#include <hip/hip_runtime.h>
#include <cstdint>
#include <cstddef>

#define T_SEQ 2048
#define BATCH 16
#define DIM   512
#define HID   512
#define KTOT  1024            // D + H
#define NCOL  2048            // 4H per direction
#define APAD  8
#define AROW  (KTOT + APAD)   // 1032 bf16 elems per A row

typedef __attribute__((ext_vector_type(8))) short          s8v;
typedef __attribute__((ext_vector_type(4))) float          f4v;
typedef __attribute__((ext_vector_type(4))) unsigned short h4v;

#define HXBASE(d, s) (((size_t)((d) * 2 + (s)) * BATCH) * HID)

__device__ __forceinline__ unsigned short f2b(float f) {
  unsigned u = __builtin_bit_cast(unsigned, f);
  return (unsigned short)((u + 0x7fffu + ((u >> 16) & 1u)) >> 16);  // RNE
}

#define MFMA16(a, w, c) __builtin_amdgcn_mfma_f32_16x16x32_bf16((a), (w), (c), 0, 0, 0)

// grid = 64 wgs x 256 thr. wg w: dir = w>>5, j-block = (w&31)*16.
// R5 structure (verified 5.72ms) + two verified deltas:
//  - gate-packed cols {gate, j0+4wv+q} + 2-round shfl_xor 4x4 transpose
//    (no glds LDS round-trip, 2 syncs/step, earlier publish)
//  - poll loads issued BEFORE x-staging so staging hides under load flight
// h exchange: epoch-tagged bf16 u32 in d_ws, ping-pong slots, relaxed
// agent-scope ld/st, tight poll with 2^16 guard (never hang).
__global__ __launch_bounds__(256, 1)
void lstm_persist(const float* __restrict__ x, const int* __restrict__ lengths,
                  const float* __restrict__ Wi_f, const float* __restrict__ Wh_f,
                  const float* __restrict__ b_f,
                  const float* __restrict__ Wi_b, const float* __restrict__ Wh_b,
                  const float* __restrict__ b_b,
                  unsigned int* __restrict__ hx,
                  float* __restrict__ out) {
  __shared__ unsigned short A[BATCH][AROW];   // [b][ x(0..512) | h(512..1024) ]

  const int w    = (int)blockIdx.x;
  const int dir  = w >> 5;
  const int j0   = (w & 31) * 16;
  const int tid  = (int)threadIdx.x;
  const int lane = tid & 63;
  const int wv   = tid >> 6;

  // staging/poll mapping: one (b, sub) per thread
  const int b   = tid >> 4;
  const int sub = tid & 15;
  const int len = lengths[b];

  // gate-math mapping (post-transpose): one (bm, jm) per thread
  const int bm   = 4 * (lane >> 4) + ((lane >> 2) & 3);
  const int jm   = j0 + 4 * wv + (lane & 3);
  const int lenm = lengths[bm];

  const float* bias = dir ? b_b : b_f;
  const float bi = bias[0 * HID + jm];
  const float bf = bias[1 * HID + jm];
  const float bg = bias[2 * HID + jm];
  const float bo = bias[3 * HID + jm];

  // ---- persistent W fragments (gate-packed cols), fp32 -> bf16 ----
  // fragment col c = lane&15 -> global col ((c>>2)*HID + j0 + 4*wv + (c&3))
  s8v wf[32];
  {
    const float* Wi = dir ? Wi_b : Wi_f;
    const float* Wh = dir ? Wh_b : Wh_f;
    const int colW = ((lane >> 2) & 3) * HID + j0 + 4 * wv + (lane & 3);
    const int kb   = (lane >> 4) * 8;
#pragma unroll
    for (int kc = 0; kc < 16; ++kc) {
      const float* src = Wi + (size_t)(kc * 32 + kb) * NCOL + colW;
      s8v f;
#pragma unroll
      for (int j = 0; j < 8; ++j) f[j] = (short)f2b(src[(size_t)j * NCOL]);
      wf[kc] = f;
    }
#pragma unroll
    for (int kc = 0; kc < 16; ++kc) {
      const float* src = Wh + (size_t)(kc * 32 + kb) * NCOL + colW;
      s8v f;
#pragma unroll
      for (int j = 0; j < 8; ++j) f[j] = (short)f2b(src[(size_t)j * NCOL]);
      wf[16 + kc] = f;
    }
  }

  const int arow = lane & 15;
  const int koff = (lane >> 4) * 8;

  // ---- prologue: stage A = [x_tau(0) | 0] ----
  {
    const int tau0 = dir ? ((T_SEQ - 1 + len) & (T_SEQ - 1)) : 0;
    const float* xrow = x + ((size_t)b * T_SEQ + tau0) * DIM;
#pragma unroll
    for (int r = 0; r < 8; ++r) {
      const int k = sub * 4 + r * 64;
      f4v v = *(const f4v*)(xrow + k);
      h4v p; p[0] = f2b(v[0]); p[1] = f2b(v[1]); p[2] = f2b(v[2]); p[3] = f2b(v[3]);
      *(h4v*)&A[b][k] = p;
      h4v z = (h4v){0, 0, 0, 0};
      *(h4v*)&A[b][DIM + k] = z;
    }
  }
  __syncthreads();

  float c_state = 0.f;

  for (int t = 0; t < T_SEQ; ++t) {
    const unsigned e = (unsigned)(t + 1);
    const bool notlast = (t + 1 < T_SEQ);

    // ---- prefetch x(t+1): flies under MFMA + gates ----
    f4v xv[8];
    if (notlast) {
      const int taun = dir ? ((T_SEQ - 2 - t + len) & (T_SEQ - 1)) : (t + 1);
      const float* xrow = x + ((size_t)b * T_SEQ + taun) * DIM;
#pragma unroll
      for (int r = 0; r < 8; ++r) xv[r] = *(const f4v*)(xrow + sub * 4 + r * 64);
    }

    // ---- MFMA: 16x16 gate-packed tile over K=1024, 4 chains ----
    f4v acc;
    {
      f4v d0 = {0,0,0,0}, d1 = {0,0,0,0}, d2 = {0,0,0,0}, d3 = {0,0,0,0};
      const unsigned short* ap = &A[arow][koff];
#pragma unroll
      for (int kc = 0; kc < 32; kc += 4) {
        d0 = MFMA16(*(const s8v*)(ap + (kc + 0) * 32), wf[kc + 0], d0);
        d1 = MFMA16(*(const s8v*)(ap + (kc + 1) * 32), wf[kc + 1], d1);
        d2 = MFMA16(*(const s8v*)(ap + (kc + 2) * 32), wf[kc + 2], d2);
        d3 = MFMA16(*(const s8v*)(ap + (kc + 3) * 32), wf[kc + 3], d3);
      }
      acc = (d0 + d1) + (d2 + d3);
    }

    // ---- 4x4 in-wave transpose: gate bits <-> batch-low bits ----
    {
      const int gb0 = (lane >> 2) & 1;
      float t0 = __shfl_xor(gb0 ? acc[0] : acc[1], 4);
      float t1 = __shfl_xor(gb0 ? acc[2] : acc[3], 4);
      if (gb0) { acc[0] = t0; acc[2] = t1; } else { acc[1] = t0; acc[3] = t1; }
      const int gb1 = (lane >> 3) & 1;
      float u0 = __shfl_xor(gb1 ? acc[0] : acc[2], 8);
      float u1 = __shfl_xor(gb1 ? acc[1] : acc[3], 8);
      if (gb1) { acc[0] = u0; acc[1] = u1; } else { acc[2] = u0; acc[3] = u1; }
      // acc[g] = gate g for (bm, jm)
    }

    // ---- gate math (one (bm, jm) per thread); publish h ASAP ----
    {
      const float gi = acc[0] + bi;
      const float gf = acc[1] + bf;
      const float gg = acc[2] + bg;
      const float go = acc[3] + bo;
      const float si = 1.f / (1.f + __expf(-gi));
      const float sf = 1.f / (1.f + __expf(-gf));
      const float so = 1.f / (1.f + __expf(-go));
      const float tg = 1.f - 2.f / (1.f + __expf(2.f * gg));
      c_state = sf * c_state + si * tg;
      const float tc = 1.f - 2.f / (1.f + __expf(2.f * c_state));
      const float h = so * tc;
      if (notlast) {
        const unsigned tagged = ((unsigned)f2b(h) << 16) | e;
        __hip_atomic_store(&hx[HXBASE(dir, e & 1) + (size_t)bm * HID + jm], tagged,
                           __ATOMIC_RELAXED, __HIP_MEMORY_SCOPE_AGENT);
      }
      const int tauo = dir ? ((T_SEQ - 1 - t + lenm) & (T_SEQ - 1)) : t;
      out[((size_t)bm * T_SEQ + tauo) * (2 * HID) + (size_t)dir * HID + jm] = h;
    }

    if (!notlast) break;

    __syncthreads();   // SYNC-A: A fully consumed by all waves

    // ---- issue poll loads FIRST (fly under x staging) ----
    const unsigned* hrow = hx + HXBASE(dir, e & 1) + (size_t)b * HID;
    unsigned long long hu[16];
#pragma unroll
    for (int r = 0; r < 8; ++r) {
      const int k = sub * 4 + r * 64;
      hu[2*r]   = __hip_atomic_load((const unsigned long long*)(hrow + k),
                                    __ATOMIC_RELAXED, __HIP_MEMORY_SCOPE_AGENT);
      hu[2*r+1] = __hip_atomic_load((const unsigned long long*)(hrow + k) + 1,
                                    __ATOMIC_RELAXED, __HIP_MEMORY_SCOPE_AGENT);
    }

    // ---- stage x(t+1) into A (x part) while polls fly ----
#pragma unroll
    for (int r = 0; r < 8; ++r) {
      const int k = sub * 4 + r * 64;
      h4v p; p[0] = f2b(xv[r][0]); p[1] = f2b(xv[r][1]);
             p[2] = f2b(xv[r][2]); p[3] = f2b(xv[r][3]);
      *(h4v*)&A[b][k] = p;
    }

    // ---- check tags; retry until h(t) complete (guard: never hang) ----
    {
      const unsigned long long msk = 0x0000FFFF0000FFFFULL;
      const unsigned long long pat = ((unsigned long long)e << 32) | e;
      int guard = 0;
      while (true) {
        bool ok = true;
#pragma unroll
        for (int r = 0; r < 16; ++r) ok &= ((hu[r] & msk) == pat);
        if (ok | (++guard > (1 << 16))) break;
        __builtin_amdgcn_s_sleep(1);
#pragma unroll
        for (int r = 0; r < 8; ++r) {
          const int k = sub * 4 + r * 64;
          hu[2*r]   = __hip_atomic_load((const unsigned long long*)(hrow + k),
                                        __ATOMIC_RELAXED, __HIP_MEMORY_SCOPE_AGENT);
          hu[2*r+1] = __hip_atomic_load((const unsigned long long*)(hrow + k) + 1,
                                        __ATOMIC_RELAXED, __HIP_MEMORY_SCOPE_AGENT);
        }
      }
    }

    // ---- stage h(t) -> A (h part) ----
#pragma unroll
    for (int r = 0; r < 8; ++r) {
      const int k = sub * 4 + r * 64;
      h4v p;
      p[0] = (unsigned short)(hu[2*r]   >> 16);
      p[1] = (unsigned short)(hu[2*r]   >> 48);
      p[2] = (unsigned short)(hu[2*r+1] >> 16);
      p[3] = (unsigned short)(hu[2*r+1] >> 48);
      *(h4v*)&A[b][DIM + k] = p;
    }
    __syncthreads();   // SYNC-B: next step's A staged
  }
}

extern "C" void kernel_launch(void* const* d_in, const int* in_sizes, int n_in,
                              void* d_out, int out_size, void* d_ws, size_t ws_size,
                              hipStream_t stream) {
  const float* x    = (const float*)d_in[0];
  const int*   len  = (const int*)d_in[1];
  const float* Wi_f = (const float*)d_in[2];
  const float* Wh_f = (const float*)d_in[3];
  const float* b_f  = (const float*)d_in[4];
  const float* Wi_b = (const float*)d_in[5];
  const float* Wh_b = (const float*)d_in[6];
  const float* b_b  = (const float*)d_in[7];
  float* out = (float*)d_out;
  unsigned int* hx = (unsigned int*)d_ws;   // [2][2][16][512] u32 = 128 KiB

  hipMemsetAsync(d_ws, 0, (size_t)2 * 2 * BATCH * HID * 4, stream);
  hipLaunchKernelGGL(lstm_persist, dim3(64), dim3(256), 0, stream,
                     x, len, Wi_f, Wh_f, b_f, Wi_b, Wh_b, b_b, hx, out);
}

// Round 10
// 5907.874 us; speedup vs baseline: 3.4183x; 1.0831x over previous
//
#include <hip/hip_runtime.h>
#include <cstdint>
#include <cstddef>

#define T_SEQ 2048
#define BATCH 16
#define DIM   512
#define HID   512
#define NCOL  2048            // 4H per direction
#define XROW  520             // 512 + 8 pad (bf16 elems)

typedef __attribute__((ext_vector_type(8))) short          s8v;
typedef __attribute__((ext_vector_type(4))) float          f4v;
typedef __attribute__((ext_vector_type(4))) unsigned short h4v;

#define HXBASE(d, s) (((size_t)((d) * 2 + (s)) * BATCH) * HID)

__device__ __forceinline__ unsigned short f2b(float f) {
  unsigned u = __builtin_bit_cast(unsigned, f);
  return (unsigned short)((u + 0x7fffu + ((u >> 16) & 1u)) >> 16);  // RNE
}

#define MFMA16(a, w, c) __builtin_amdgcn_mfma_f32_16x16x32_bf16((a), (w), (c), 0, 0, 0)

// grid = 64 wgs x 256 thr. wg w: dir = w>>5, j-block = (w&31)*16.
// R5 gate path (wave wv = gate wv, glds LDS exchange, coalesced (b,sub)
// publish/out — R9 proved the transpose/scatter variant costs +0.33us/step)
// + split-K: x(t+1)*Wi runs in step t's tail off the critical path, reading
// a double-buffered x tile staged two iters ahead. Critical path is only
// stage-h -> sync -> 16 h-MFMAs (seeded with accx) -> glds -> gates.
// h exchange: epoch-tagged bf16 u32 in d_ws, ping-pong slots, relaxed
// agent-scope ld/st, early-issue/late-check poll, 2^14 guard (never hang).
__global__ __launch_bounds__(256, 1)
void lstm_persist(const float* __restrict__ x, const int* __restrict__ lengths,
                  const float* __restrict__ Wi_f, const float* __restrict__ Wh_f,
                  const float* __restrict__ b_f,
                  const float* __restrict__ Wi_b, const float* __restrict__ Wh_b,
                  const float* __restrict__ b_b,
                  unsigned int* __restrict__ hx,
                  float* __restrict__ out) {
  __shared__ unsigned short Ax[2][BATCH][XROW];  // x tiles, double-buffered
  __shared__ unsigned short Ah[BATCH][XROW];     // h(t-1) tile
  __shared__ float glds[4][BATCH][16];           // gate exchange

  const int w    = (int)blockIdx.x;
  const int dir  = w >> 5;
  const int j0   = (w & 31) * 16;
  const int tid  = (int)threadIdx.x;
  const int lane = tid & 63;
  const int wv   = tid >> 6;

  const int b   = tid >> 4;   // one (b, sub) per thread: staging, gates, publish
  const int sub = tid & 15;
  const int len = lengths[b];

  const float* bias = dir ? b_b : b_f;
  const float bi = bias[0 * HID + j0 + sub];
  const float bf = bias[1 * HID + j0 + sub];
  const float bg = bias[2 * HID + j0 + sub];
  const float bo = bias[3 * HID + j0 + sub];

  // ---- persistent W fragments (R5 layout: wave wv = gate wv) ----
  s8v wfi[16], wfh[16];
  {
    const float* Wi = dir ? Wi_b : Wi_f;
    const float* Wh = dir ? Wh_b : Wh_f;
    const int col = wv * HID + j0 + (lane & 15);
    const int kb  = (lane >> 4) * 8;
#pragma unroll
    for (int kc = 0; kc < 16; ++kc) {
      const float* src = Wi + (size_t)(kc * 32 + kb) * NCOL + col;
      s8v f;
#pragma unroll
      for (int j = 0; j < 8; ++j) f[j] = (short)f2b(src[(size_t)j * NCOL]);
      wfi[kc] = f;
    }
#pragma unroll
    for (int kc = 0; kc < 16; ++kc) {
      const float* src = Wh + (size_t)(kc * 32 + kb) * NCOL + col;
      s8v f;
#pragma unroll
      for (int j = 0; j < 8; ++j) f[j] = (short)f2b(src[(size_t)j * NCOL]);
      wfh[kc] = f;
    }
  }

  const int arow = lane & 15;
  const int koff = (lane >> 4) * 8;

  auto taus = [len, dir](int s) { return dir ? ((T_SEQ - 1 - s + len) & (T_SEQ - 1)) : s; };

  // ---- prologue: stage x(tau(0)) -> Ax[0], x(tau(1)) -> Ax[1] ----
  {
    const float* x0 = x + ((size_t)b * T_SEQ + taus(0)) * DIM;
    const float* x1 = x + ((size_t)b * T_SEQ + taus(1)) * DIM;
#pragma unroll
    for (int r = 0; r < 8; ++r) {
      const int k = sub * 4 + r * 64;
      f4v v0 = *(const f4v*)(x0 + k);
      f4v v1 = *(const f4v*)(x1 + k);
      h4v p0; p0[0] = f2b(v0[0]); p0[1] = f2b(v0[1]); p0[2] = f2b(v0[2]); p0[3] = f2b(v0[3]);
      h4v p1; p1[0] = f2b(v1[0]); p1[1] = f2b(v1[1]); p1[2] = f2b(v1[2]); p1[3] = f2b(v1[3]);
      *(h4v*)&Ax[0][b][k] = p0;
      *(h4v*)&Ax[1][b][k] = p1;
    }
  }
  __syncthreads();

  // ---- accx for t = 0 ----
  f4v accx;
  {
    f4v d0 = {0,0,0,0}, d1 = {0,0,0,0}, d2 = {0,0,0,0}, d3 = {0,0,0,0};
    const unsigned short* ap = &Ax[0][arow][koff];
#pragma unroll
    for (int kc = 0; kc < 16; kc += 4) {
      d0 = MFMA16(*(const s8v*)(ap + (kc + 0) * 32), wfi[kc + 0], d0);
      d1 = MFMA16(*(const s8v*)(ap + (kc + 1) * 32), wfi[kc + 1], d1);
      d2 = MFMA16(*(const s8v*)(ap + (kc + 2) * 32), wfi[kc + 2], d2);
      d3 = MFMA16(*(const s8v*)(ap + (kc + 3) * 32), wfi[kc + 3], d3);
    }
    accx = (d0 + d1) + (d2 + d3);
  }

  float c_state = 0.f;

  for (int t = 0; t < T_SEQ; ++t) {
    const unsigned e = (unsigned)(t + 1);
    const bool notlast = (t + 1 < T_SEQ);

    // ---- prefetch x(t+2): consumed in this iter's tail staging ----
    f4v xv[8];
    if (t + 2 < T_SEQ) {
      const float* xr = x + ((size_t)b * T_SEQ + taus(t + 2)) * DIM;
#pragma unroll
      for (int r = 0; r < 8; ++r) xv[r] = *(const f4v*)(xr + sub * 4 + r * 64);
    }

    // ---- critical-path MFMA: h(t-1)*Wh (K=512), seeded with accx ----
    f4v acc;
    {
      f4v d0 = accx, d1 = {0,0,0,0}, d2 = {0,0,0,0}, d3 = {0,0,0,0};
      if (t > 0) {
        const unsigned short* ap = &Ah[arow][koff];
#pragma unroll
        for (int kc = 0; kc < 16; kc += 4) {
          d0 = MFMA16(*(const s8v*)(ap + (kc + 0) * 32), wfh[kc + 0], d0);
          d1 = MFMA16(*(const s8v*)(ap + (kc + 1) * 32), wfh[kc + 1], d1);
          d2 = MFMA16(*(const s8v*)(ap + (kc + 2) * 32), wfh[kc + 2], d2);
          d3 = MFMA16(*(const s8v*)(ap + (kc + 3) * 32), wfh[kc + 3], d3);
        }
      }
      acc = (d0 + d1) + (d2 + d3);
    }
#pragma unroll
    for (int r = 0; r < 4; ++r)
      glds[wv][(lane >> 4) * 4 + r][lane & 15] = acc[r];
    __syncthreads();   // SYNC-A: glds ready; Ah/Ax reads of this iter done

    // ---- gate math (one (b, j0+sub) per thread); coalesced publish ----
    {
      const float gi = glds[0][b][sub] + bi;
      const float gf = glds[1][b][sub] + bf;
      const float gg = glds[2][b][sub] + bg;
      const float go = glds[3][b][sub] + bo;
      const float si = 1.f / (1.f + __expf(-gi));
      const float sf = 1.f / (1.f + __expf(-gf));
      const float so = 1.f / (1.f + __expf(-go));
      const float tg = 1.f - 2.f / (1.f + __expf(2.f * gg));
      c_state = sf * c_state + si * tg;
      const float tc = 1.f - 2.f / (1.f + __expf(2.f * c_state));
      const float h = so * tc;
      if (notlast) {
        const unsigned tagged = ((unsigned)f2b(h) << 16) | e;
        __hip_atomic_store(&hx[HXBASE(dir, e & 1) + (size_t)b * HID + j0 + sub], tagged,
                           __ATOMIC_RELAXED, __HIP_MEMORY_SCOPE_AGENT);
      }
      const int tauo = dir ? ((T_SEQ - 1 - t + len) & (T_SEQ - 1)) : t;
      out[((size_t)b * T_SEQ + tauo) * (2 * HID) + (size_t)dir * HID + j0 + sub] = h;
    }

    if (!notlast) break;

    // ---- issue poll loads for h(t) (early-issue, late-check) ----
    const unsigned* hrow = hx + HXBASE(dir, e & 1) + (size_t)b * HID;
    unsigned long long hu[16];
#pragma unroll
    for (int r = 0; r < 8; ++r) {
      const int k = sub * 4 + r * 64;
      hu[2*r]   = __hip_atomic_load((const unsigned long long*)(hrow + k),
                                    __ATOMIC_RELAXED, __HIP_MEMORY_SCOPE_AGENT);
      hu[2*r+1] = __hip_atomic_load((const unsigned long long*)(hrow + k) + 1,
                                    __ATOMIC_RELAXED, __HIP_MEMORY_SCOPE_AGENT);
    }

    // ---- tail x-MFMA: accx = x(t+1)*Wi (off critical path) ----
    {
      f4v d0 = {0,0,0,0}, d1 = {0,0,0,0}, d2 = {0,0,0,0}, d3 = {0,0,0,0};
      const unsigned short* ap = &Ax[(t + 1) & 1][arow][koff];
#pragma unroll
      for (int kc = 0; kc < 16; kc += 4) {
        d0 = MFMA16(*(const s8v*)(ap + (kc + 0) * 32), wfi[kc + 0], d0);
        d1 = MFMA16(*(const s8v*)(ap + (kc + 1) * 32), wfi[kc + 1], d1);
        d2 = MFMA16(*(const s8v*)(ap + (kc + 2) * 32), wfi[kc + 2], d2);
        d3 = MFMA16(*(const s8v*)(ap + (kc + 3) * 32), wfi[kc + 3], d3);
      }
      accx = (d0 + d1) + (d2 + d3);
    }

    // ---- stage x(t+2) -> Ax[t&1] (poll loads fly meanwhile) ----
    if (t + 2 < T_SEQ) {
#pragma unroll
      for (int r = 0; r < 8; ++r) {
        const int k = sub * 4 + r * 64;
        h4v p; p[0] = f2b(xv[r][0]); p[1] = f2b(xv[r][1]);
               p[2] = f2b(xv[r][2]); p[3] = f2b(xv[r][3]);
        *(h4v*)&Ax[t & 1][b][k] = p;
      }
    }

    // ---- check tags; retry until h(t) complete (guard: never hang) ----
    {
      const unsigned long long msk = 0x0000FFFF0000FFFFULL;
      const unsigned long long pat = ((unsigned long long)e << 32) | e;
      int guard = 0;
      while (true) {
        bool ok = true;
#pragma unroll
        for (int r = 0; r < 16; ++r) ok &= ((hu[r] & msk) == pat);
        if (ok | (++guard > (1 << 14))) break;
        __builtin_amdgcn_s_sleep(1);
#pragma unroll
        for (int r = 0; r < 8; ++r) {
          const int k = sub * 4 + r * 64;
          hu[2*r]   = __hip_atomic_load((const unsigned long long*)(hrow + k),
                                        __ATOMIC_RELAXED, __HIP_MEMORY_SCOPE_AGENT);
          hu[2*r+1] = __hip_atomic_load((const unsigned long long*)(hrow + k) + 1,
                                        __ATOMIC_RELAXED, __HIP_MEMORY_SCOPE_AGENT);
        }
      }
    }

    // ---- stage h(t) -> Ah ----
#pragma unroll
    for (int r = 0; r < 8; ++r) {
      const int k = sub * 4 + r * 64;
      h4v p;
      p[0] = (unsigned short)(hu[2*r]   >> 16);
      p[1] = (unsigned short)(hu[2*r]   >> 48);
      p[2] = (unsigned short)(hu[2*r+1] >> 16);
      p[3] = (unsigned short)(hu[2*r+1] >> 48);
      *(h4v*)&Ah[b][k] = p;
    }
    __syncthreads();   // SYNC-B: Ah + Ax staged for next iteration
  }
}

extern "C" void kernel_launch(void* const* d_in, const int* in_sizes, int n_in,
                              void* d_out, int out_size, void* d_ws, size_t ws_size,
                              hipStream_t stream) {
  const float* x    = (const float*)d_in[0];
  const int*   len  = (const int*)d_in[1];
  const float* Wi_f = (const float*)d_in[2];
  const float* Wh_f = (const float*)d_in[3];
  const float* b_f  = (const float*)d_in[4];
  const float* Wi_b = (const float*)d_in[5];
  const float* Wh_b = (const float*)d_in[6];
  const float* b_b  = (const float*)d_in[7];
  float* out = (float*)d_out;
  unsigned int* hx = (unsigned int*)d_ws;   // [2][2][16][512] u32 = 128 KiB

  hipMemsetAsync(d_ws, 0, (size_t)2 * 2 * BATCH * HID * 4, stream);
  hipLaunchKernelGGL(lstm_persist, dim3(64), dim3(256), 0, stream,
                     x, len, Wi_f, Wh_f, b_f, Wi_b, Wh_b, b_b, hx, out);
}